// Round 1
// baseline (3404.430 us; speedup 1.0000x reference)
//
#include <hip/hip_runtime.h>
#include <math.h>

// ---------------------------------------------------------------------------
// Problem constants
//   x: (16,32,256,256) f32, weight_raw: (32,32,3,3), bias: (32,)
//   u1:(1,32,1,3) u2:(1,32,3,1) u3:(1,32,3,3) u4:(32,1,3,3)
//   out: (16,32,256,256) f32
// Pipeline: skew -> fantastic_four (3 power iters) -> conv_exp (11x11) ->
//           circular 11x11 conv + bias.
// ---------------------------------------------------------------------------

__device__ __forceinline__ float block_sum256(float v, float* red) {
    #pragma unroll
    for (int off = 32; off > 0; off >>= 1)
        v += __shfl_down(v, off, 64);
    const int tid = threadIdx.x;
    if ((tid & 63) == 0) red[tid >> 6] = v;
    __syncthreads();
    float tot = red[0] + red[1] + red[2] + red[3];
    __syncthreads();
    return tot;
}

// L2-normalize an LDS array in place:  a /= (sqrt(sum(a^2)) + 1e-12)
__device__ __forceinline__ void l2n_lds(float* a, int n, float* red) {
    float s = 0.f;
    for (int i = threadIdx.x; i < n; i += 256) s += a[i] * a[i];
    const float tot = block_sum256(s, red);
    const float sc = 1.0f / (sqrtf(tot) + 1e-12f);
    for (int i = threadIdx.x; i < n; i += 256) a[i] *= sc;
    __syncthreads();
}

// ---------------------------------------------------------------------------
// Kernel A: skew + fantastic_four.  Single block, everything in LDS.
// Writes normalized 3x3 kernel (layout [o][i][p][q], 9216 floats) to kf_out.
// ---------------------------------------------------------------------------
__global__ __launch_bounds__(256) void ff_kernel(
    const float* __restrict__ wr,
    const float* __restrict__ u1g, const float* __restrict__ u2g,
    const float* __restrict__ u3g, const float* __restrict__ u4g,
    float* __restrict__ kf_out)
{
    __shared__ float ks[9216];
    __shared__ float u1[96], v1[96], u2[96], v2[96];
    __shared__ float u3[288], u4[288], v3[32], v4[32];
    __shared__ float red[8];
    const int tid = threadIdx.x;

    // skew: ks[o,i,p,q] = w[o,i,p,q] - w[i,o,2-p,2-q]
    for (int i = tid; i < 9216; i += 256) {
        int q  = i % 3;
        int p  = (i / 3) % 3;
        int ic = (i / 9) % 32;
        int oc = i / 288;
        ks[i] = wr[i] - wr[ic * 288 + oc * 9 + (2 - p) * 3 + (2 - q)];
    }
    if (tid < 96) { u1[tid] = u1g[tid]; u2[tid] = u2g[tid]; }
    for (int i = tid; i < 288; i += 256) { u3[i] = u3g[i]; u4[i] = u4g[i]; }
    __syncthreads();
    l2n_lds(u1, 96, red);
    l2n_lds(u2, 96, red);
    l2n_lds(u3, 288, red);
    l2n_lds(u4, 288, red);

    for (int it = 0; it < 3; ++it) {
        // v1[o,p] = sum_{i,q} ks[o,i,p,q] * u1[i,q]
        if (tid < 96) {
            int o = tid / 3, p = tid % 3;
            float s = 0.f;
            for (int i = 0; i < 32; ++i)
                for (int q = 0; q < 3; ++q)
                    s += ks[o * 288 + i * 9 + p * 3 + q] * u1[i * 3 + q];
            v1[tid] = s;
        }
        __syncthreads();
        l2n_lds(v1, 96, red);
        // u1[i,q] = sum_{o,p} ks[o,i,p,q] * v1[o,p]
        if (tid < 96) {
            int i = tid / 3, q = tid % 3;
            float s = 0.f;
            for (int o = 0; o < 32; ++o)
                for (int p = 0; p < 3; ++p)
                    s += ks[o * 288 + i * 9 + p * 3 + q] * v1[o * 3 + p];
            u1[tid] = s;
        }
        __syncthreads();
        l2n_lds(u1, 96, red);
        // v2[o,q] = sum_{i,p} ks[o,i,p,q] * u2[i,p]
        if (tid < 96) {
            int o = tid / 3, q = tid % 3;
            float s = 0.f;
            for (int i = 0; i < 32; ++i)
                for (int p = 0; p < 3; ++p)
                    s += ks[o * 288 + i * 9 + p * 3 + q] * u2[i * 3 + p];
            v2[tid] = s;
        }
        __syncthreads();
        l2n_lds(v2, 96, red);
        // u2[i,p] = sum_{o,q} ks[o,i,p,q] * v2[o,q]
        if (tid < 96) {
            int i = tid / 3, p = tid % 3;
            float s = 0.f;
            for (int o = 0; o < 32; ++o)
                for (int q = 0; q < 3; ++q)
                    s += ks[o * 288 + i * 9 + p * 3 + q] * v2[o * 3 + q];
            u2[tid] = s;
        }
        __syncthreads();
        l2n_lds(u2, 96, red);
        // v3[o] = sum_{i,p,q} ks * u3[i,p,q]
        if (tid < 32) {
            float s = 0.f;
            for (int i = 0; i < 32; ++i)
                for (int pq = 0; pq < 9; ++pq)
                    s += ks[tid * 288 + i * 9 + pq] * u3[i * 9 + pq];
            v3[tid] = s;
        }
        __syncthreads();
        l2n_lds(v3, 32, red);
        // u3[i,p,q] = sum_o ks[o, i,p,q] * v3[o]
        for (int j = tid; j < 288; j += 256) {
            float s = 0.f;
            for (int o = 0; o < 32; ++o)
                s += ks[o * 288 + j] * v3[o];
            u3[j] = s;
        }
        __syncthreads();
        l2n_lds(u3, 288, red);
        // v4[i] = sum_{o,p,q} ks * u4[o,p,q]
        if (tid < 32) {
            float s = 0.f;
            for (int o = 0; o < 32; ++o)
                for (int pq = 0; pq < 9; ++pq)
                    s += ks[o * 288 + tid * 9 + pq] * u4[o * 9 + pq];
            v4[tid] = s;
        }
        __syncthreads();
        l2n_lds(v4, 32, red);
        // u4[o,p,q] = sum_i ks[o,i,p,q] * v4[i]
        for (int j = tid; j < 288; j += 256) {
            int o = j / 9, pq = j - o * 9;
            float s = 0.f;
            for (int i = 0; i < 32; ++i)
                s += ks[o * 288 + i * 9 + pq] * v4[i];
            u4[j] = s;
        }
        __syncthreads();
        l2n_lds(u4, 288, red);
    }

    // sigmas (use final u's and last-computed v's, per reference ordering)
    float p1 = 0.f, p2 = 0.f, p3 = 0.f, p4 = 0.f;
    for (int idx = tid; idx < 9216; idx += 256) {
        int q = idx % 3;
        int p = (idx / 3) % 3;
        int i = (idx / 9) % 32;
        int o = idx / 288;
        float k = ks[idx];
        p1 += k * u1[i * 3 + q] * v1[o * 3 + p];
        p2 += k * u2[i * 3 + p] * v2[o * 3 + q];
        p3 += k * u3[i * 9 + p * 3 + q] * v3[o];
        p4 += k * u4[o * 9 + p * 3 + q] * v4[i];
    }
    float s1 = block_sum256(p1, red);
    float s2 = block_sum256(p2, red);
    float s3 = block_sum256(p3, red);
    float s4 = block_sum256(p4, red);
    float sigma = fminf(fminf(s1, s2), fminf(s3, s4));
    for (int idx = tid; idx < 9216; idx += 256)
        kf_out[idx] = ks[idx] / sigma;
}

// ---------------------------------------------------------------------------
// wacc init: identity (center) + base kernel centered in 11x11.
// wacc layout: [o][c][11][11]
// ---------------------------------------------------------------------------
__global__ void initacc_kernel(const float* __restrict__ kf, float* __restrict__ wacc) {
    int idx = blockIdx.x * 256 + threadIdx.x;
    if (idx >= 123904) return;
    int o = idx / 3872;
    int rem = idx - o * 3872;
    int c = rem / 121;
    int yx = rem - c * 121;
    int y = yx / 11, x = yx - y * 11;
    float v = (o == c && y == 5 && x == 5) ? 1.0f : 0.0f;
    if (y >= 4 && y <= 6 && x >= 4 && x <= 6)
        v += kf[o * 288 + c * 9 + (y - 4) * 3 + (x - 4)];
    wacc[idx] = v;
}

// ---------------------------------------------------------------------------
// conv-exponential step i: ki_new[o,d,y,x] = (1/i) sum_{c,p,q} kf[o,c,p,q]
//   * ki[c,d,y-p,x-q]; also accumulates into wacc centered at off=(11-S2)/2.
// ki/ko layout: [first][second][S][S] flattened as (a*32+b)*S*S.
// ---------------------------------------------------------------------------
__global__ void expstep_kernel(const float* __restrict__ kf, const float* __restrict__ ki,
                               float* __restrict__ ko, float* __restrict__ wacc,
                               int S, float scale)
{
    const int S2 = S + 2;
    const int off = (11 - S2) >> 1;
    const int o = blockIdx.x >> 5;
    const int d = blockIdx.x & 31;
    for (int yx = threadIdx.x; yx < S2 * S2; yx += blockDim.x) {
        int y = yx / S2, xx = yx - y * S2;
        float s = 0.f;
        for (int c = 0; c < 32; ++c) {
            const float* kfo = kf + o * 288 + c * 9;
            const float* kic = ki + (c * 32 + d) * S * S;
            #pragma unroll
            for (int p = 0; p < 3; ++p) {
                int yy = y - p;
                if (yy < 0 || yy >= S) continue;
                #pragma unroll
                for (int q = 0; q < 3; ++q) {
                    int xq = xx - q;
                    if (xq < 0 || xq >= S) continue;
                    s += kfo[p * 3 + q] * kic[yy * S + xq];
                }
            }
        }
        s *= scale;
        ko[(o * 32 + d) * S2 * S2 + yx] = s;
        wacc[(o * 32 + d) * 121 + (y + off) * 11 + (xx + off)] += s;
    }
}

// ---------------------------------------------------------------------------
// Transpose wacc [o][c][11][11] -> wt [c][p*11+q][o]  (conv staging layout)
// ---------------------------------------------------------------------------
__global__ void wtrans_kernel(const float* __restrict__ wacc, float* __restrict__ wt) {
    int idx = blockIdx.x * 256 + threadIdx.x;
    if (idx >= 123904) return;
    int c = idx / 3872;
    int rem = idx - c * 3872;
    int pq = rem >> 5;
    int o = rem & 31;
    wt[idx] = wacc[o * 3872 + c * 121 + pq];
}

// ---------------------------------------------------------------------------
// Main conv: circular 11x11, fp32 direct conv.
// Block = 256 threads -> one batch, all 32 o-channels, 16(y) x 32(x) tile.
// Per input channel: patch (26x42, LDS stride 44 -> 16B-aligned rows) +
// weights [pq][o] (121x32) staged in LDS. Each thread: 8 o x 8 x register
// block; 20-float sliding window over q.  0.61 B LDS / FMA -> VALU-bound.
// ---------------------------------------------------------------------------
__global__ __launch_bounds__(256, 3) void conv_main_kernel(
    const float* __restrict__ x, const float* __restrict__ wt,
    const float* __restrict__ bias, float* __restrict__ out)
{
    __shared__ float patch[26 * 44];
    __shared__ float wl[121 * 32];
    const int b   = blockIdx.z;
    const int Y0  = blockIdx.y << 4;   // 16 rows per tile
    const int X0  = blockIdx.x << 5;   // 32 cols per tile
    const int tid = threadIdx.x;
    const int obase = (tid & 3) << 3;        // 8 o-channels
    const int Xl    = ((tid >> 2) & 3) << 3; // 8 x-positions
    const int yl    = tid >> 4;              // 1 y-row (0..15)

    float acc[8][8];
    #pragma unroll
    for (int k = 0; k < 8; ++k)
        #pragma unroll
        for (int j = 0; j < 8; ++j) acc[k][j] = 0.f;

    for (int c = 0; c < 32; ++c) {
        __syncthreads();
        // stage input patch with circular wrap (H=W=256 -> mask &255)
        const float* xc = x + (((size_t)b * 32 + c) << 16);
        for (int idx = tid; idx < 26 * 42; idx += 256) {
            int r = idx / 42;
            int s = idx - r * 42;
            int gy = (Y0 + r - 5) & 255;
            int gx = (X0 + s - 5) & 255;
            patch[r * 44 + s] = xc[(gy << 8) + gx];
        }
        // stage weights for this input channel: wt[c][pq][o]
        const float* wc = wt + c * 3872;
        for (int idx = tid; idx < 3872; idx += 256)
            wl[idx] = wc[idx];
        __syncthreads();

        #pragma unroll 1
        for (int p = 0; p < 11; ++p) {
            float rr[20];
            const float* prow = &patch[(yl + p) * 44 + Xl];
            #pragma unroll
            for (int k = 0; k < 5; ++k) {
                float4 v = *(const float4*)(prow + 4 * k);
                rr[4 * k + 0] = v.x; rr[4 * k + 1] = v.y;
                rr[4 * k + 2] = v.z; rr[4 * k + 3] = v.w;
            }
            #pragma unroll
            for (int q = 0; q < 11; ++q) {
                const float* wrow = &wl[(p * 11 + q) * 32 + obase];
                float4 w0 = *(const float4*)(wrow);
                float4 w1 = *(const float4*)(wrow + 4);
                float wreg[8] = {w0.x, w0.y, w0.z, w0.w, w1.x, w1.y, w1.z, w1.w};
                #pragma unroll
                for (int k = 0; k < 8; ++k)
                    #pragma unroll
                    for (int j = 0; j < 8; ++j)
                        acc[k][j] += rr[j + q] * wreg[k];
            }
        }
    }

    const int oy = Y0 + yl;
    const int ox = X0 + Xl;
    #pragma unroll
    for (int k = 0; k < 8; ++k) {
        int o = obase + k;
        float bv = bias[o];
        float* orow = out + ((((size_t)b * 32 + o) << 16) + (oy << 8) + ox);
        float4 s0 = make_float4(acc[k][0] + bv, acc[k][1] + bv,
                                acc[k][2] + bv, acc[k][3] + bv);
        float4 s1 = make_float4(acc[k][4] + bv, acc[k][5] + bv,
                                acc[k][6] + bv, acc[k][7] + bv);
        *(float4*)(orow) = s0;
        *(float4*)(orow + 4) = s1;
    }
}

// ---------------------------------------------------------------------------
extern "C" void kernel_launch(void* const* d_in, const int* in_sizes, int n_in,
                              void* d_out, int out_size, void* d_ws, size_t ws_size,
                              hipStream_t stream) {
    const float* x    = (const float*)d_in[0];
    const float* wraw = (const float*)d_in[1];
    const float* bias = (const float*)d_in[2];
    const float* u1   = (const float*)d_in[3];
    const float* u2   = (const float*)d_in[4];
    const float* u3   = (const float*)d_in[5];
    const float* u4   = (const float*)d_in[6];
    float* out = (float*)d_out;

    float* ws   = (float*)d_ws;
    float* kf   = ws;               // 9216
    float* bufA = kf + 9216;        // 123904
    float* bufB = bufA + 123904;    // 123904
    float* wacc = bufB + 123904;    // 123904
    float* wt   = wacc + 123904;    // 123904

    ff_kernel<<<1, 256, 0, stream>>>(wraw, u1, u2, u3, u4, kf);
    initacc_kernel<<<484, 256, 0, stream>>>(kf, wacc);
    // conv_exp: ki_1 = kf (3x3), steps i=2..5
    expstep_kernel<<<1024, 128, 0, stream>>>(kf, kf,   bufA, wacc, 3, 0.5f);
    expstep_kernel<<<1024, 128, 0, stream>>>(kf, bufA, bufB, wacc, 5, 1.0f / 3.0f);
    expstep_kernel<<<1024, 128, 0, stream>>>(kf, bufB, bufA, wacc, 7, 0.25f);
    expstep_kernel<<<1024, 128, 0, stream>>>(kf, bufA, bufB, wacc, 9, 0.2f);
    wtrans_kernel<<<484, 256, 0, stream>>>(wacc, wt);

    conv_main_kernel<<<dim3(8, 16, 16), 256, 0, stream>>>(x, wt, bias, out);
}

// Round 2
// 924.748 us; speedup vs baseline: 3.6815x; 3.6815x over previous
//
#include <hip/hip_runtime.h>
#include <math.h>

typedef __bf16 bf16x8 __attribute__((ext_vector_type(8)));
typedef float f32x16 __attribute__((ext_vector_type(16)));
typedef unsigned int uint4v __attribute__((ext_vector_type(4)));

__device__ __forceinline__ unsigned short bf16_rne(float f) {
    unsigned u = __float_as_uint(f);
    unsigned r = u + 0x7fffu + ((u >> 16) & 1u);
    return (unsigned short)(r >> 16);
}
__device__ __forceinline__ float bf16_to_f(unsigned short h) {
    return __uint_as_float(((unsigned)h) << 16);
}

// ---------------------------------------------------------------------------
__device__ __forceinline__ float block_sum256(float v, float* red) {
    #pragma unroll
    for (int off = 32; off > 0; off >>= 1)
        v += __shfl_down(v, off, 64);
    const int tid = threadIdx.x;
    if ((tid & 63) == 0) red[tid >> 6] = v;
    __syncthreads();
    float tot = red[0] + red[1] + red[2] + red[3];
    __syncthreads();
    return tot;
}

__device__ __forceinline__ void l2n_lds(float* a, int n, float* red) {
    float s = 0.f;
    for (int i = threadIdx.x; i < n; i += 256) s += a[i] * a[i];
    const float tot = block_sum256(s, red);
    const float sc = 1.0f / (sqrtf(tot) + 1e-12f);
    for (int i = threadIdx.x; i < n; i += 256) a[i] *= sc;
    __syncthreads();
}

// ---------------------------------------------------------------------------
// skew + fantastic_four -> kf (layout [o][i][3][3])
// ---------------------------------------------------------------------------
__global__ __launch_bounds__(256) void ff_kernel(
    const float* __restrict__ wr,
    const float* __restrict__ u1g, const float* __restrict__ u2g,
    const float* __restrict__ u3g, const float* __restrict__ u4g,
    float* __restrict__ kf_out)
{
    __shared__ float ks[9216];
    __shared__ float u1[96], v1[96], u2[96], v2[96];
    __shared__ float u3[288], u4[288], v3[32], v4[32];
    __shared__ float red[8];
    const int tid = threadIdx.x;

    for (int i = tid; i < 9216; i += 256) {
        int q  = i % 3;
        int p  = (i / 3) % 3;
        int ic = (i / 9) % 32;
        int oc = i / 288;
        ks[i] = wr[i] - wr[ic * 288 + oc * 9 + (2 - p) * 3 + (2 - q)];
    }
    if (tid < 96) { u1[tid] = u1g[tid]; u2[tid] = u2g[tid]; }
    for (int i = tid; i < 288; i += 256) { u3[i] = u3g[i]; u4[i] = u4g[i]; }
    __syncthreads();
    l2n_lds(u1, 96, red);
    l2n_lds(u2, 96, red);
    l2n_lds(u3, 288, red);
    l2n_lds(u4, 288, red);

    for (int it = 0; it < 3; ++it) {
        if (tid < 96) {
            int o = tid / 3, p = tid % 3;
            float s = 0.f;
            for (int i = 0; i < 32; ++i)
                for (int q = 0; q < 3; ++q)
                    s += ks[o * 288 + i * 9 + p * 3 + q] * u1[i * 3 + q];
            v1[tid] = s;
        }
        __syncthreads();
        l2n_lds(v1, 96, red);
        if (tid < 96) {
            int i = tid / 3, q = tid % 3;
            float s = 0.f;
            for (int o = 0; o < 32; ++o)
                for (int p = 0; p < 3; ++p)
                    s += ks[o * 288 + i * 9 + p * 3 + q] * v1[o * 3 + p];
            u1[tid] = s;
        }
        __syncthreads();
        l2n_lds(u1, 96, red);
        if (tid < 96) {
            int o = tid / 3, q = tid % 3;
            float s = 0.f;
            for (int i = 0; i < 32; ++i)
                for (int p = 0; p < 3; ++p)
                    s += ks[o * 288 + i * 9 + p * 3 + q] * u2[i * 3 + p];
            v2[tid] = s;
        }
        __syncthreads();
        l2n_lds(v2, 96, red);
        if (tid < 96) {
            int i = tid / 3, p = tid % 3;
            float s = 0.f;
            for (int o = 0; o < 32; ++o)
                for (int q = 0; q < 3; ++q)
                    s += ks[o * 288 + i * 9 + p * 3 + q] * v2[o * 3 + q];
            u2[tid] = s;
        }
        __syncthreads();
        l2n_lds(u2, 96, red);
        if (tid < 32) {
            float s = 0.f;
            for (int i = 0; i < 32; ++i)
                for (int pq = 0; pq < 9; ++pq)
                    s += ks[tid * 288 + i * 9 + pq] * u3[i * 9 + pq];
            v3[tid] = s;
        }
        __syncthreads();
        l2n_lds(v3, 32, red);
        for (int j = tid; j < 288; j += 256) {
            float s = 0.f;
            for (int o = 0; o < 32; ++o)
                s += ks[o * 288 + j] * v3[o];
            u3[j] = s;
        }
        __syncthreads();
        l2n_lds(u3, 288, red);
        if (tid < 32) {
            float s = 0.f;
            for (int o = 0; o < 32; ++o)
                for (int pq = 0; pq < 9; ++pq)
                    s += ks[o * 288 + tid * 9 + pq] * u4[o * 9 + pq];
            v4[tid] = s;
        }
        __syncthreads();
        l2n_lds(v4, 32, red);
        for (int j = tid; j < 288; j += 256) {
            int o = j / 9, pq = j - o * 9;
            float s = 0.f;
            for (int i = 0; i < 32; ++i)
                s += ks[o * 288 + i * 9 + pq] * v4[i];
            u4[j] = s;
        }
        __syncthreads();
        l2n_lds(u4, 288, red);
    }

    float p1 = 0.f, p2 = 0.f, p3 = 0.f, p4 = 0.f;
    for (int idx = tid; idx < 9216; idx += 256) {
        int q = idx % 3;
        int p = (idx / 3) % 3;
        int i = (idx / 9) % 32;
        int o = idx / 288;
        float k = ks[idx];
        p1 += k * u1[i * 3 + q] * v1[o * 3 + p];
        p2 += k * u2[i * 3 + p] * v2[o * 3 + q];
        p3 += k * u3[i * 9 + p * 3 + q] * v3[o];
        p4 += k * u4[o * 9 + p * 3 + q] * v4[i];
    }
    float s1 = block_sum256(p1, red);
    float s2 = block_sum256(p2, red);
    float s3 = block_sum256(p3, red);
    float s4 = block_sum256(p4, red);
    float sigma = fminf(fminf(s1, s2), fminf(s3, s4));
    for (int idx = tid; idx < 9216; idx += 256)
        kf_out[idx] = ks[idx] / sigma;
}

// ---------------------------------------------------------------------------
// wacc init: identity + base kernel centered in 11x11. wacc layout [o][c][11][11]
// ---------------------------------------------------------------------------
__global__ void initacc_kernel(const float* __restrict__ kf, float* __restrict__ wacc) {
    int idx = blockIdx.x * 256 + threadIdx.x;
    if (idx >= 123904) return;
    int o = idx / 3872;
    int rem = idx - o * 3872;
    int c = rem / 121;
    int yx = rem - c * 121;
    int y = yx / 11, x = yx - y * 11;
    float v = (o == c && y == 5 && x == 5) ? 1.0f : 0.0f;
    if (y >= 4 && y <= 6 && x >= 4 && x <= 6)
        v += kf[o * 288 + c * 9 + (y - 4) * 3 + (x - 4)];
    wacc[idx] = v;
}

// ---------------------------------------------------------------------------
// conv-exponential step
// ---------------------------------------------------------------------------
__global__ void expstep_kernel(const float* __restrict__ kf, const float* __restrict__ ki,
                               float* __restrict__ ko, float* __restrict__ wacc,
                               int S, float scale)
{
    const int S2 = S + 2;
    const int off = (11 - S2) >> 1;
    const int o = blockIdx.x >> 5;
    const int d = blockIdx.x & 31;
    for (int yx = threadIdx.x; yx < S2 * S2; yx += blockDim.x) {
        int y = yx / S2, xx = yx - y * S2;
        float s = 0.f;
        for (int c = 0; c < 32; ++c) {
            const float* kfo = kf + o * 288 + c * 9;
            const float* kic = ki + (c * 32 + d) * S * S;
            #pragma unroll
            for (int p = 0; p < 3; ++p) {
                int yy = y - p;
                if (yy < 0 || yy >= S) continue;
                #pragma unroll
                for (int q = 0; q < 3; ++q) {
                    int xq = xx - q;
                    if (xq < 0 || xq >= S) continue;
                    s += kfo[p * 3 + q] * kic[yy * S + xq];
                }
            }
        }
        s *= scale;
        ko[(o * 32 + d) * S2 * S2 + yx] = s;
        wacc[(o * 32 + d) * 121 + (y + off) * 11 + (xx + off)] += s;
    }
}

// ---------------------------------------------------------------------------
// Weight prepack: wacc [o][c][11][11] fp32 -> wbuf bf16 A-fragments.
// Frag index = ((tap*2 + chalf)*2 + split)*64 + lane ; each entry = uint4
// (8 bf16): lane(m=lane&31, khalf=lane>>5), j -> c = chalf*16 + khalf*8 + j.
// split 0 = bf16 hi, split 1 = bf16 lo (residual).
// ---------------------------------------------------------------------------
__global__ void wprep_kernel(const float* __restrict__ wacc, uint4v* __restrict__ wbuf) {
    int idx = blockIdx.x * 256 + threadIdx.x;   // 121*2*2*64 = 30976
    if (idx >= 30976) return;
    int lane  = idx & 63;
    int split = (idx >> 6) & 1;
    int ch    = (idx >> 7) & 1;
    int tap   = idx >> 8;                       // p*11+q
    int o     = lane & 31;
    int cbase = ch * 16 + ((lane >> 5) << 3);
    unsigned short v[8];
    #pragma unroll
    for (int j = 0; j < 8; ++j) {
        float w = wacc[o * 3872 + (cbase + j) * 121 + tap];
        unsigned short h = bf16_rne(w);
        v[j] = split ? bf16_rne(w - bf16_to_f(h)) : h;
    }
    uint4v u;
    u.x = (unsigned)v[0] | ((unsigned)v[1] << 16);
    u.y = (unsigned)v[2] | ((unsigned)v[3] << 16);
    u.z = (unsigned)v[4] | ((unsigned)v[5] << 16);
    u.w = (unsigned)v[6] | ((unsigned)v[7] << 16);
    wbuf[idx] = u;
}

// ---------------------------------------------------------------------------
// Main conv via bf16-split MFMA (w=whi+wlo, x=xhi+xlo; 3 MFMAs per tap/c-half:
// Ahi*Bhi + Alo*Bhi + Ahi*Blo = w*x - wlo*xlo, rel err ~2^-16).
// Block: 4 waves, out tile 32x(X) x 16y, all 32 o. Wave: 4 rows x 32 px,
// acc = 4 D-frags (16 f32 each). x staged per c-half as LDS pixel-major
// [pixel][16c] bf16 hi/lo planes (patch 26x42). Weights read from global
// prepacked frags (L2-resident), software-pipelined one tap ahead.
// mfma_f32_32x32x16_bf16: A[m=lane&31][k=(lane>>5)*8+j], B[k][n=lane&31],
// D: col=lane&31, row=(r&3)+8*(r>>2)+4*(lane>>5)  [m74/m101 verified C/D].
// ---------------------------------------------------------------------------
__global__ __launch_bounds__(256, 2) void conv_mfma_kernel(
    const float* __restrict__ x, const uint4v* __restrict__ wbuf,
    const float* __restrict__ bias, float* __restrict__ out)
{
    __shared__ unsigned short shi[1092 * 16];   // 26*42 px * 16c (hi)
    __shared__ unsigned short slo[1092 * 16];   // (lo)
    __shared__ float biasS[32];

    const int b    = blockIdx.z;
    const int Y0   = blockIdx.y << 4;
    const int X0   = blockIdx.x << 5;
    const int tid  = threadIdx.x;
    const int lane = tid & 63;
    const int ywave = (tid >> 6) << 2;               // wave's first out row
    const int myoff = ((lane & 31) << 1) + (lane >> 5); // 16B-unit offset

    if (tid < 32) biasS[tid] = bias[tid];

    f32x16 acc[4];
    #pragma unroll
    for (int s = 0; s < 4; ++s)
        #pragma unroll
        for (int r = 0; r < 16; ++r) acc[s][r] = 0.f;

    const uint4v* ph = (const uint4v*)shi;
    const uint4v* pl = (const uint4v*)slo;

    for (int chlf = 0; chlf < 2; ++chlf) {
        __syncthreads();   // previous tap-loop readers done before restage
        // ---- stage patch (c-half), circular wrap, bf16 split ----
        const float* xb = x + (((size_t)(b * 32 + chlf * 16)) << 16);
        for (int pix = tid; pix < 1092; pix += 256) {
            int r = pix / 42, s = pix - r * 42;
            int gy = (Y0 + r - 5) & 255;
            int gx = (X0 + s - 5) & 255;
            const float* xp = xb + (gy << 8) + gx;
            unsigned short hv[16], lv[16];
            #pragma unroll
            for (int cc = 0; cc < 16; ++cc) {
                float v = xp[(size_t)cc << 16];
                unsigned short h = bf16_rne(v);
                hv[cc] = h;
                lv[cc] = bf16_rne(v - bf16_to_f(h));
            }
            uint4v u;
            u.x = (unsigned)hv[0] | ((unsigned)hv[1] << 16);
            u.y = (unsigned)hv[2] | ((unsigned)hv[3] << 16);
            u.z = (unsigned)hv[4] | ((unsigned)hv[5] << 16);
            u.w = (unsigned)hv[6] | ((unsigned)hv[7] << 16);
            *(uint4v*)&shi[pix * 16] = u;
            u.x = (unsigned)hv[8]  | ((unsigned)hv[9]  << 16);
            u.y = (unsigned)hv[10] | ((unsigned)hv[11] << 16);
            u.z = (unsigned)hv[12] | ((unsigned)hv[13] << 16);
            u.w = (unsigned)hv[14] | ((unsigned)hv[15] << 16);
            *(uint4v*)&shi[pix * 16 + 8] = u;
            u.x = (unsigned)lv[0] | ((unsigned)lv[1] << 16);
            u.y = (unsigned)lv[2] | ((unsigned)lv[3] << 16);
            u.z = (unsigned)lv[4] | ((unsigned)lv[5] << 16);
            u.w = (unsigned)lv[6] | ((unsigned)lv[7] << 16);
            *(uint4v*)&slo[pix * 16] = u;
            u.x = (unsigned)lv[8]  | ((unsigned)lv[9]  << 16);
            u.y = (unsigned)lv[10] | ((unsigned)lv[11] << 16);
            u.z = (unsigned)lv[12] | ((unsigned)lv[13] << 16);
            u.w = (unsigned)lv[14] | ((unsigned)lv[15] << 16);
            *(uint4v*)&slo[pix * 16 + 8] = u;
        }
        __syncthreads();

        // ---- 121-tap MFMA loop, A software-pipelined from global ----
        const int wb0 = chlf * 128 + lane;
        uint4v a0 = wbuf[wb0];
        uint4v a1 = wbuf[wb0 + 64];
        #pragma unroll 1
        for (int tap = 0; tap < 121; ++tap) {
            bf16x8 Ahi = __builtin_bit_cast(bf16x8, a0);
            bf16x8 Alo = __builtin_bit_cast(bf16x8, a1);
            if (tap < 120) {
                a0 = wbuf[wb0 + (tap + 1) * 256];
                a1 = wbuf[wb0 + (tap + 1) * 256 + 64];
            }
            int p = tap / 11, q = tap - p * 11;
            int u0 = ((ywave + p) * 42 + q) * 2 + myoff;
            #pragma unroll
            for (int s = 0; s < 4; ++s) {
                bf16x8 Bh = __builtin_bit_cast(bf16x8, ph[u0 + s * 84]);
                bf16x8 Bl = __builtin_bit_cast(bf16x8, pl[u0 + s * 84]);
                acc[s] = __builtin_amdgcn_mfma_f32_32x32x16_bf16(Ahi, Bh, acc[s], 0, 0, 0);
                acc[s] = __builtin_amdgcn_mfma_f32_32x32x16_bf16(Alo, Bh, acc[s], 0, 0, 0);
                acc[s] = __builtin_amdgcn_mfma_f32_32x32x16_bf16(Ahi, Bl, acc[s], 0, 0, 0);
            }
        }
    }

    // ---- epilogue: bias + store (lane = x col, reg -> o channel) ----
    const int colx = X0 + (lane & 31);
    const int half = lane >> 5;
    #pragma unroll
    for (int s = 0; s < 4; ++s) {
        int y = Y0 + ywave + s;
        #pragma unroll
        for (int r = 0; r < 16; ++r) {
            int o = (r & 3) + ((r >> 2) << 3) + (half << 2);
            out[(((size_t)(b * 32 + o)) << 16) + (y << 8) + colx] = acc[s][r] + biasS[o];
        }
    }
}

// ---------------------------------------------------------------------------
extern "C" void kernel_launch(void* const* d_in, const int* in_sizes, int n_in,
                              void* d_out, int out_size, void* d_ws, size_t ws_size,
                              hipStream_t stream) {
    const float* x    = (const float*)d_in[0];
    const float* wraw = (const float*)d_in[1];
    const float* bias = (const float*)d_in[2];
    const float* u1   = (const float*)d_in[3];
    const float* u2   = (const float*)d_in[4];
    const float* u3   = (const float*)d_in[5];
    const float* u4   = (const float*)d_in[6];
    float* out = (float*)d_out;

    float* ws   = (float*)d_ws;
    float* kf   = ws;               // 9216
    float* bufA = kf + 9216;        // 123904
    float* bufB = bufA + 123904;    // 123904
    float* wacc = bufB + 123904;    // 123904
    uint4v* wbuf = (uint4v*)(wacc + 123904);  // 30976 uint4 = 495616 B

    ff_kernel<<<1, 256, 0, stream>>>(wraw, u1, u2, u3, u4, kf);
    initacc_kernel<<<484, 256, 0, stream>>>(kf, wacc);
    expstep_kernel<<<1024, 128, 0, stream>>>(kf, kf,   bufA, wacc, 3, 0.5f);
    expstep_kernel<<<1024, 128, 0, stream>>>(kf, bufA, bufB, wacc, 5, 1.0f / 3.0f);
    expstep_kernel<<<1024, 128, 0, stream>>>(kf, bufB, bufA, wacc, 7, 0.25f);
    expstep_kernel<<<1024, 128, 0, stream>>>(kf, bufA, bufB, wacc, 9, 0.2f);
    wprep_kernel<<<121, 256, 0, stream>>>(wacc, wbuf);

    conv_mfma_kernel<<<dim3(8, 16, 16), 256, 0, stream>>>(x, wbuf, bias, out);
}